// Round 2
// 573.191 us; speedup vs baseline: 1.0060x; 1.0060x over previous
//
#include <hip/hip_runtime.h>
#include <hip/hip_bf16.h>

// ============================================================================
// Hybrid matrix prefix scan:  res[k] = x @ (m_0 ... m_{k-1}),  N=1024, D=256.
// Deviation form everywhere: store P - I in bf16; combine is exact:
//   dev(XY) = devX + devY + devX@devY.
// Round 5 (recompile fix: __builtin_bit_cast -> __builtin_memcpy, since
// __hip_bfloat162 is not trivially copyable on this ROCm):
//  (a) gemm: A fragments loaded straight to registers (lane l of wave w owns
//      MFMA row m0+16w+(l&15)) -> A LDS eliminated, LDS 64->32 KiB, occupancy
//      2->4 blocks/CU (__launch_bounds__(256,4)); K-loop ds_read 40->32/wave.
//      Epilogue devA re-read from global (L2-hot via XCD swizzle).
//  (b) native packed bf16 converts (v_cvt_pk_bf16_f32 via hip_bf16 casts).
//  (c) tail_fused: scan_top8 + 5 descend levels + bottom in ONE kernel
//      (256 WGs; per-WG greedy span descent, identical op order -> identical
//      numerics), killing 6 dependent small-grid launches.
//  (d) wide up-sweep (1 launch per level) when ws >= 127 MiB; old half-split
//      narrow path kept as fallback; fallback_seq if ws tiny.
// ============================================================================

#define D 256
#define DD 65536

typedef __attribute__((ext_vector_type(8))) short short8;
typedef __attribute__((ext_vector_type(4))) float f4;

__device__ __forceinline__ float bf2f(unsigned short u) {
  return __uint_as_float(((unsigned)u) << 16);
}
// native RNE converts -- compiler emits v_cvt_pk_bf16_f32 (learn_hip m240)
__device__ __forceinline__ unsigned short f2bf(float f) {
  __hip_bfloat16 h = __float2bfloat16(f);
  unsigned short u;
  __builtin_memcpy(&u, &h, 2);
  return u;
}
__device__ __forceinline__ unsigned f2bf2(float lo, float hi) {
  __hip_bfloat162 h = __float22bfloat162_rn(make_float2(lo, hi));
  unsigned u;
  __builtin_memcpy(&u, &h, 4);
  return u;
}
// fragment-order slot lane index (see R3): frag reads lane-contiguous b128.
#define LSWZ(i15, lq) (((((i15) & 15)) + ((lq) << 4)) ^ (lq))

// out[mat] = devA + devB + devA@devB (bf16 dev out), MFMA 16x16x32 bf16.
// 64x64 tile/block (16 blocks/mat), 4 waves. B staged full-K in LDS (32 KiB);
// A fragments live in registers. Block swizzle: xcd = bx&7; all 16 tiles of a
// mat on the same XCD (requires gridDim/16 divisible by 8).
__global__ __launch_bounds__(256, 4) void gemm_mfma(
    const float* __restrict__ aF, const unsigned short* __restrict__ aBf,
    long aMul, long aOff,
    const float* __restrict__ bF, const unsigned short* __restrict__ bBf,
    long bMul, long bOff,
    unsigned short* __restrict__ out)
{
  __shared__ __attribute__((aligned(16))) unsigned short Bs[16384]; // 32 KiB

  const int  bx  = blockIdx.x;
  const int  nmb = ((int)gridDim.x) >> 4;         // mats this dispatch (mult of 8)
  const int  xcd = bx & 7, q = bx >> 3;
  const long mat = (long)(xcd * (nmb >> 3)) + (q >> 4);
  const int  tile = q & 15;
  const int  m0 = (tile >> 2) << 6, n0 = (tile & 3) << 6;
  const long aBase = (mat * aMul + aOff) * (long)DD;
  const long bBase = (mat * bMul + bOff) * (long)DD;
  const int t = threadIdx.x;
  const int w = t >> 6, l = t & 63, lm = l & 15, lq4 = l >> 4;
  const int lswz = l ^ lq4;

  // ---- A fragments straight to registers.
  // Lane l of wave w feeds MFMA row R = m0+16w+(l&15), k = 32kt + 8*lq4 + j.
  const int R = m0 + (w << 4) + lm;
  short8 areg[8];
  if (aF) {
    const float* ap = aF + aBase + (long)R * D + (lq4 << 3);
#pragma unroll
    for (int kt = 0; kt < 8; ++kt) {
      const int k0 = (kt << 5) + (lq4 << 3);
      const float4 v0 = *(const float4*)(ap + (kt << 5));
      const float4 v1 = *(const float4*)(ap + (kt << 5) + 4);
      union { short8 v8; unsigned u[4]; } ou;
      ou.u[0] = f2bf2(v0.x - ((R == k0 + 0) ? 1.f : 0.f),
                      v0.y - ((R == k0 + 1) ? 1.f : 0.f));
      ou.u[1] = f2bf2(v0.z - ((R == k0 + 2) ? 1.f : 0.f),
                      v0.w - ((R == k0 + 3) ? 1.f : 0.f));
      ou.u[2] = f2bf2(v1.x - ((R == k0 + 4) ? 1.f : 0.f),
                      v1.y - ((R == k0 + 5) ? 1.f : 0.f));
      ou.u[3] = f2bf2(v1.z - ((R == k0 + 6) ? 1.f : 0.f),
                      v1.w - ((R == k0 + 7) ? 1.f : 0.f));
      areg[kt] = ou.v8;
    }
  } else {
    const unsigned short* ap = aBf + aBase + (long)R * D + (lq4 << 3);
#pragma unroll
    for (int kt = 0; kt < 8; ++kt)
      areg[kt] = *(const short8*)(ap + (kt << 5));
  }

  // ---- stage B cols [n0,n0+64) x k[0,256) (register transpose into LDS)
  {
    const int n4 = (t & 15) << 2;
    const int kb0 = (t >> 4) << 3;
#pragma unroll
    for (int kp = 0; kp < 2; ++kp) {
      const int k8 = kb0 + (kp << 7);
      const int lq = (k8 >> 3) & 3, kt = k8 >> 5;
      if (bF) {
        unsigned tmpu[4][4];
#pragma unroll
        for (int kk = 0; kk < 8; kk += 2) {
          const int gka = k8 + kk, gkb = gka + 1, gn = n0 + n4;
          float4 va = *(const float4*)(bF + bBase + (long)gka * D + gn);
          float4 vb = *(const float4*)(bF + bBase + (long)gkb * D + gn);
          va.x -= (gka == gn + 0) ? 1.f : 0.f;
          va.y -= (gka == gn + 1) ? 1.f : 0.f;
          va.z -= (gka == gn + 2) ? 1.f : 0.f;
          va.w -= (gka == gn + 3) ? 1.f : 0.f;
          vb.x -= (gkb == gn + 0) ? 1.f : 0.f;
          vb.y -= (gkb == gn + 1) ? 1.f : 0.f;
          vb.z -= (gkb == gn + 2) ? 1.f : 0.f;
          vb.w -= (gkb == gn + 3) ? 1.f : 0.f;
          tmpu[0][kk >> 1] = f2bf2(va.x, vb.x);
          tmpu[1][kk >> 1] = f2bf2(va.y, vb.y);
          tmpu[2][kk >> 1] = f2bf2(va.z, vb.z);
          tmpu[3][kk >> 1] = f2bf2(va.w, vb.w);
        }
#pragma unroll
        for (int jj = 0; jj < 4; ++jj) {
          const int n = n4 + jj;
          const int slot = (((n >> 4) << 3) + kt) * 64 + LSWZ(n, lq);
          uint4 st = { tmpu[jj][0], tmpu[jj][1], tmpu[jj][2], tmpu[jj][3] };
          *(uint4*)&Bs[slot << 3] = st;
        }
      } else {
        __attribute__((aligned(16))) unsigned short tmp[4][8];
#pragma unroll
        for (int kk = 0; kk < 8; ++kk) {
          const ushort4 v = *(const ushort4*)(bBf + bBase + (long)(k8 + kk) * D + n0 + n4);
          tmp[0][kk] = v.x; tmp[1][kk] = v.y; tmp[2][kk] = v.z; tmp[3][kk] = v.w;
        }
#pragma unroll
        for (int jj = 0; jj < 4; ++jj) {
          const int n = n4 + jj;
          const int slot = (((n >> 4) << 3) + kt) * 64 + LSWZ(n, lq);
          *(uint4*)&Bs[slot << 3] = *(const uint4*)&tmp[jj][0];
        }
      }
    }
  }
  __syncthreads();

  // ---- MFMA: A from registers, B frags lane-contiguous from LDS (32 b128)
  f4 acc[4] = {{0.f,0.f,0.f,0.f},{0.f,0.f,0.f,0.f},
               {0.f,0.f,0.f,0.f},{0.f,0.f,0.f,0.f}};
#pragma unroll
  for (int kt = 0; kt < 8; ++kt) {
#pragma unroll
    for (int f = 0; f < 4; ++f) {
      const short8 b = *(const short8*)&Bs[((((f << 3) + kt) << 6) + lswz) << 3];
      acc[f] = __builtin_amdgcn_mfma_f32_16x16x32_bf16(areg[kt], b, acc[f], 0, 0, 0);
    }
  }

  // ---- epilogue: s = acc + devA (global re-read, L2-hot) + devB (LDS)
#pragma unroll
  for (int f = 0; f < 4; ++f) {
    const int gj_l = (f << 4) + lm;
    const int gj   = n0 + gj_l;                   // A's k/col index
#pragma unroll
    for (int r = 0; r < 4; ++r) {
      const int gi_l = (w << 4) + (lq4 << 2) + r; // local row
      const int giG  = m0 + gi_l;                 // B's k index
      float da;
      if (aF)
        da = aF[aBase + (long)giG * D + gj] - ((giG == gj) ? 1.f : 0.f);
      else
        da = bf2f(aBf[aBase + (long)giG * D + gj]);
      const int lqB  = (giG >> 3) & 3;
      const int slotB = (((gj_l >> 4) << 3) + (giG >> 5)) * 64 + LSWZ(gj_l, lqB);
      const float db = bf2f(Bs[(slotB << 3) + (giG & 7)]);
      acc[f][r] += da + db;
    }
  }
  __syncthreads();                                // all Bs reads done

  // ---- C restage (pitch 66: conflict-free b16 writes) then coalesced store
  unsigned short* Cs = Bs;                        // reuse (4224 shorts)
#pragma unroll
  for (int f = 0; f < 4; ++f)
#pragma unroll
    for (int r = 0; r < 4; ++r)
      Cs[((w << 4) + (lq4 << 2) + r) * 66 + (f << 4) + lm] = f2bf(acc[f][r]);
  __syncthreads();
  {
    const int row = t >> 2, c0g = (t & 3) << 4;   // 16 shorts per thread
    const unsigned int* Cw = (const unsigned int*)Cs;
    const int wb = row * 33 + ((t & 3) << 3);
    unsigned int wbuf[8];
#pragma unroll
    for (int i = 0; i < 8; ++i) wbuf[i] = Cw[wb + i];
    unsigned short* og = out + mat * (long)DD + (long)(m0 + row) * D + n0 + c0g;
    uint4 o0 = { wbuf[0], wbuf[1], wbuf[2], wbuf[3] };
    uint4 o1 = { wbuf[4], wbuf[5], wbuf[6], wbuf[7] };
    *(uint4*)og = o0;
    *((uint4*)og + 1) = o1;
  }
}

// v = v + v @ dev(M) over one bf16 span-product; barriers are WG-uniform.
__device__ __forceinline__ void apply_bf16(const unsigned short* __restrict__ Mb,
                                           float* v, float (*ps)[D],
                                           int t, int col, int kq) {
  const unsigned short* M = Mb + (long)(kq * 64) * D + col;
  float acc = 0.f;
#pragma unroll 8
  for (int i = 0; i < 64; ++i)
    acc += v[kq * 64 + i] * bf2f(M[(long)i * D]);
  ps[kq][col] = acc;
  __syncthreads();
  if (t < D) v[t] += ps[0][t] + ps[1][t] + ps[2][t] + ps[3][t];
  __syncthreads();
}

// ONE kernel for the whole tail. WG c targets prefix length L = 4c:
// greedy span descent (128*,64,32,16,8,4 -- identical matrices in identical
// order to the old scan_top8+descend chain), then exact fp32 bottom mat-vecs
// over m emitting out rows L..L+3 (c=255 also emits row 1024).
__global__ __launch_bounds__(1024) void tail_fused(
    const float* __restrict__ x,
    const unsigned short* __restrict__ sp128, const unsigned short* __restrict__ sp64,
    const unsigned short* __restrict__ sp32,  const unsigned short* __restrict__ sp16,
    const unsigned short* __restrict__ sp8,   const unsigned short* __restrict__ sp4,
    const float* __restrict__ m, float* __restrict__ out)
{
  __shared__ float v[D];
  __shared__ float ps[4][D];
  const int c = blockIdx.x, t = threadIdx.x, col = t & 255, kq = t >> 8;
  if (t < D) v[t] = x[t];
  __syncthreads();
  const int L = c << 2;

  int pos = 0;
#pragma unroll 1
  while (pos + 128 <= L) { apply_bf16(sp128 + (long)(pos >> 7) * DD, v, ps, t, col, kq); pos += 128; }
  if (pos + 64 <= L) { apply_bf16(sp64 + (long)(pos >> 6) * DD, v, ps, t, col, kq); pos += 64; }
  if (pos + 32 <= L) { apply_bf16(sp32 + (long)(pos >> 5) * DD, v, ps, t, col, kq); pos += 32; }
  if (pos + 16 <= L) { apply_bf16(sp16 + (long)(pos >> 4) * DD, v, ps, t, col, kq); pos += 16; }
  if (pos + 8 <= L)  { apply_bf16(sp8  + (long)(pos >> 3) * DD, v, ps, t, col, kq); pos += 8; }
  if (pos + 4 <= L)  { apply_bf16(sp4  + (long)(pos >> 2) * DD, v, ps, t, col, kq); pos += 4; }

  // bottom: emit rows with exact fp32 mat-vecs over m
  if (t < D) out[(long)L * D + t] = v[t];
  const int steps = (c == 255) ? 4 : 3;
#pragma unroll 1
  for (int s = 0; s < steps; ++s) {
    const float* M = m + (long)(L + s) * DD + (long)(kq * 64) * D + col;
    float acc = 0.f;
#pragma unroll 8
    for (int i = 0; i < 64; ++i)
      acc += v[kq * 64 + i] * M[(long)i * D];
    ps[kq][col] = acc;
    __syncthreads();
    if (t < D) {
      const float s2 = ps[0][t] + ps[1][t] + ps[2][t] + ps[3][t];
      v[t] = s2;
      out[(long)(L + s + 1) * D + t] = s2;
    }
    __syncthreads();
  }
}

// correctness-only fallback if ws is too small: fully sequential chain
__global__ __launch_bounds__(256) void fallback_seq(
    const float* __restrict__ x, const float* __restrict__ m,
    float* __restrict__ out)
{
  __shared__ float v[D];
  const int t = threadIdx.x;
  v[t] = x[t];
  __syncthreads();
  for (int k = 0; k < 1024; ++k) {
    out[(long)k * D + t] = v[t];
    const float* M = m + (long)k * DD;
    float acc = 0.f;
    for (int i = 0; i < D; ++i) acc += v[i] * M[(long)i * D + t];
    __syncthreads();
    v[t] = acc;
    __syncthreads();
  }
  out[(long)1024 * D + t] = v[t];
}

extern "C" void kernel_launch(void* const* d_in, const int* in_sizes, int n_in,
                              void* d_out, int out_size, void* d_ws, size_t ws_size,
                              hipStream_t stream) {
  const float* x = (const float*)d_in[0];   // [1,256] fp32
  const float* m = (const float*)d_in[1];   // [1024,256,256] fp32
  float* out = (float*)d_out;               // [1025,256] fp32

  char* w8 = (char*)d_ws;
  const size_t MB = 1048576;
  const dim3 blk(256), vblk(1024);

  if (ws_size >= 127 * MB) {
    // ---- wide path: full-width tree, one launch per level (7 gemms + tail)
    unsigned short* T2   = (unsigned short*)(w8);             // 64 MiB span-2  (512)
    unsigned short* Qb   = (unsigned short*)(w8 + 64 * MB);   // 32 MiB span-4  (256)
    unsigned short* Q2   = (unsigned short*)(w8 + 96 * MB);   // 16 MiB span-8  (128)
    unsigned short* Q4   = (unsigned short*)(w8 + 112 * MB);  //  8 MiB span-16 (64)
    unsigned short* Rm   = (unsigned short*)(w8 + 120 * MB);  //  4 MiB span-32 (32)
    unsigned short* S64  = (unsigned short*)(w8 + 124 * MB);  //  2 MiB span-64 (16)
    unsigned short* S128 = (unsigned short*)(w8 + 126 * MB);  //  1 MiB span-128 (8)
    gemm_mfma<<<dim3(8192), blk, 0, stream>>>(m, nullptr, 2, 0, m, nullptr, 2, 1, T2);
    gemm_mfma<<<dim3(4096), blk, 0, stream>>>(nullptr, T2, 2, 0, nullptr, T2, 2, 1, Qb);
    gemm_mfma<<<dim3(2048), blk, 0, stream>>>(nullptr, Qb, 2, 0, nullptr, Qb, 2, 1, Q2);
    gemm_mfma<<<dim3(1024), blk, 0, stream>>>(nullptr, Q2, 2, 0, nullptr, Q2, 2, 1, Q4);
    gemm_mfma<<<dim3(512),  blk, 0, stream>>>(nullptr, Q4, 2, 0, nullptr, Q4, 2, 1, Rm);
    gemm_mfma<<<dim3(256),  blk, 0, stream>>>(nullptr, Rm, 2, 0, nullptr, Rm, 2, 1, S64);
    gemm_mfma<<<dim3(128),  blk, 0, stream>>>(nullptr, S64, 2, 0, nullptr, S64, 2, 1, S128);
    tail_fused<<<dim3(256), vblk, 0, stream>>>(x, S128, S64, Rm, Q4, Q2, Qb, m, out);
  } else if (ws_size >= 67108864) {
    // ---- narrow path (previous round's half-split tree), fused tail
    unsigned short* buf0 = (unsigned short*)(w8);
    unsigned short* Qb   = (unsigned short*)(w8 + 33554432);  // span-4, 256 mats
    unsigned short* Q2   = (unsigned short*)(w8);             // 16 MiB span-8
    unsigned short* Q4   = (unsigned short*)(w8 + 16777216);  //  8 MiB span-16
    unsigned short* Rm   = (unsigned short*)(w8 + 25165824);  //  4 MiB span-32
    unsigned short* S64  = (unsigned short*)(w8 + 29360128);  //  2 MiB span-64
    unsigned short* S128 = (unsigned short*)(w8 + 31457280);  //  1 MiB span-128
    gemm_mfma<<<dim3(4096), blk, 0, stream>>>(m, nullptr, 2, 0, m, nullptr, 2, 1, buf0);
    gemm_mfma<<<dim3(2048), blk, 0, stream>>>(nullptr, buf0, 2, 0, nullptr, buf0, 2, 1, Qb);
    gemm_mfma<<<dim3(4096), blk, 0, stream>>>(m + 512L * DD, nullptr, 2, 0,
                                              m + 512L * DD, nullptr, 2, 1, buf0);
    gemm_mfma<<<dim3(2048), blk, 0, stream>>>(nullptr, buf0, 2, 0, nullptr, buf0, 2, 1,
                                              Qb + 128L * DD);
    gemm_mfma<<<dim3(2048), blk, 0, stream>>>(nullptr, Qb, 2, 0, nullptr, Qb, 2, 1, Q2);
    gemm_mfma<<<dim3(1024), blk, 0, stream>>>(nullptr, Q2, 2, 0, nullptr, Q2, 2, 1, Q4);
    gemm_mfma<<<dim3(512),  blk, 0, stream>>>(nullptr, Q4, 2, 0, nullptr, Q4, 2, 1, Rm);
    gemm_mfma<<<dim3(256),  blk, 0, stream>>>(nullptr, Rm, 2, 0, nullptr, Rm, 2, 1, S64);
    gemm_mfma<<<dim3(128),  blk, 0, stream>>>(nullptr, S64, 2, 0, nullptr, S64, 2, 1, S128);
    tail_fused<<<dim3(256), vblk, 0, stream>>>(x, S128, S64, Rm, Q4, Q2, Qb, m, out);
  } else {
    fallback_seq<<<dim3(1), blk, 0, stream>>>(x, m, out);
  }
}

// Round 3
// 571.090 us; speedup vs baseline: 1.0097x; 1.0037x over previous
//
#include <hip/hip_runtime.h>
#include <hip/hip_bf16.h>

// ============================================================================
// Hybrid matrix prefix scan:  res[k] = x @ (m_0 ... m_{k-1}),  N=1024, D=256.
// Deviation form everywhere: store P - I in bf16; combine is exact:
//   dev(XY) = devX + devY + devX@devY.
// Round 6:
//  (a) drop forced occupancy bound (256,4) -> plain (256): the 4-block cap
//      forces VGPR<=128 and may have spilled the fp32 staging path, cancelling
//      the occupancy win (R5 was a wash vs R4).
//  (b) identity-subtract hoisted out of the per-element staging path:
//      off-diagonal elements need no subtract. B: diag-block intersects a
//      lane's 4col x 8row strip iff rel=gn-k8 in {0,4}; affected components
//      are then STATIC (2 cmp + 8 sub replace ~192 VALU/thread). A: lane row
//      R's single diag element is in kt-strip iff (R>>3)==4kt+lq4; 7/8 kt
//      iters are execz-skipped (~32 VALU replace ~192). Same fp32 math, same
//      order -> bit-identical output.
//  (c) unchanged from R5: A frags direct to regs, 32 KiB LDS, packed bf16
//      cvt, fused tail, wide 8-launch tree.
// ============================================================================

#define D 256
#define DD 65536

typedef __attribute__((ext_vector_type(8))) short short8;
typedef __attribute__((ext_vector_type(4))) float f4;

__device__ __forceinline__ float bf2f(unsigned short u) {
  return __uint_as_float(((unsigned)u) << 16);
}
// native RNE converts -- compiler emits v_cvt_pk_bf16_f32 (learn_hip m240)
__device__ __forceinline__ unsigned short f2bf(float f) {
  __hip_bfloat16 h = __float2bfloat16(f);
  unsigned short u;
  __builtin_memcpy(&u, &h, 2);
  return u;
}
__device__ __forceinline__ unsigned f2bf2(float lo, float hi) {
  __hip_bfloat162 h = __float22bfloat162_rn(make_float2(lo, hi));
  unsigned u;
  __builtin_memcpy(&u, &h, 4);
  return u;
}
// fragment-order slot lane index (see R3): frag reads lane-contiguous b128.
#define LSWZ(i15, lq) (((((i15) & 15)) + ((lq) << 4)) ^ (lq))

// out[mat] = devA + devB + devA@devB (bf16 dev out), MFMA 16x16x32 bf16.
// 64x64 tile/block (16 blocks/mat), 4 waves. B staged full-K in LDS (32 KiB);
// A fragments live in registers. Block swizzle: xcd = bx&7; all 16 tiles of a
// mat on the same XCD (requires gridDim/16 divisible by 8).
__global__ __launch_bounds__(256) void gemm_mfma(
    const float* __restrict__ aF, const unsigned short* __restrict__ aBf,
    long aMul, long aOff,
    const float* __restrict__ bF, const unsigned short* __restrict__ bBf,
    long bMul, long bOff,
    unsigned short* __restrict__ out)
{
  __shared__ __attribute__((aligned(16))) unsigned short Bs[16384]; // 32 KiB

  const int  bx  = blockIdx.x;
  const int  nmb = ((int)gridDim.x) >> 4;         // mats this dispatch (mult of 8)
  const int  xcd = bx & 7, q = bx >> 3;
  const long mat = (long)(xcd * (nmb >> 3)) + (q >> 4);
  const int  tile = q & 15;
  const int  m0 = (tile >> 2) << 6, n0 = (tile & 3) << 6;
  const long aBase = (mat * aMul + aOff) * (long)DD;
  const long bBase = (mat * bMul + bOff) * (long)DD;
  const int t = threadIdx.x;
  const int w = t >> 6, l = t & 63, lm = l & 15, lq4 = l >> 4;
  const int lswz = l ^ lq4;

  // ---- A fragments straight to registers.
  // Lane l of wave w feeds MFMA row R = m0+16w+(l&15), k = 32kt + 8*lq4 + j.
  const int R = m0 + (w << 4) + lm;
  short8 areg[8];
  if (aF) {
    const float* ap = aF + aBase + (long)R * D + (lq4 << 3);
#pragma unroll
    for (int kt = 0; kt < 8; ++kt) {
      float4 v0 = *(const float4*)(ap + (kt << 5));
      float4 v1 = *(const float4*)(ap + (kt << 5) + 4);
      // diag fixup: row R's diagonal col R lies in this 8-k strip iff
      // (R>>3) == 4*kt + lq4; then the component is j = R & 7.
      if ((R >> 3) == (kt << 2) + lq4) {
        const int j = R & 7;
        if      (j == 0) v0.x -= 1.f;
        else if (j == 1) v0.y -= 1.f;
        else if (j == 2) v0.z -= 1.f;
        else if (j == 3) v0.w -= 1.f;
        else if (j == 4) v1.x -= 1.f;
        else if (j == 5) v1.y -= 1.f;
        else if (j == 6) v1.z -= 1.f;
        else             v1.w -= 1.f;
      }
      union { short8 v8; unsigned u[4]; } ou;
      ou.u[0] = f2bf2(v0.x, v0.y);
      ou.u[1] = f2bf2(v0.z, v0.w);
      ou.u[2] = f2bf2(v1.x, v1.y);
      ou.u[3] = f2bf2(v1.z, v1.w);
      areg[kt] = ou.v8;
    }
  } else {
    const unsigned short* ap = aBf + aBase + (long)R * D + (lq4 << 3);
#pragma unroll
    for (int kt = 0; kt < 8; ++kt)
      areg[kt] = *(const short8*)(ap + (kt << 5));
  }

  // ---- stage B cols [n0,n0+64) x k[0,256) (register transpose into LDS)
  {
    const int n4 = (t & 15) << 2;
    const int kb0 = (t >> 4) << 3;
    const int gn = n0 + n4;
#pragma unroll
    for (int kp = 0; kp < 2; ++kp) {
      const int k8 = kb0 + (kp << 7);
      const int lq = (k8 >> 3) & 3, kt = k8 >> 5;
      if (bF) {
        // hoist loads, apply static diag fixup, then convert
        float4 va[4], vb[4];
#pragma unroll
        for (int kk2 = 0; kk2 < 4; ++kk2) {
          va[kk2] = *(const float4*)(bF + bBase + (long)(k8 + 2 * kk2) * D + gn);
          vb[kk2] = *(const float4*)(bF + bBase + (long)(k8 + 2 * kk2 + 1) * D + gn);
        }
        // cols [gn,gn+4) have diag rows [gn,gn+4); subset of [k8,k8+8) iff
        // rel in {0,4} (gn,k8 both 4-aligned, k8 8-aligned).
        const int rel = gn - k8;
        if (rel == 0) {        // rows k8+0..3 = cols gn+0..3
          va[0].x -= 1.f; vb[0].y -= 1.f; va[1].z -= 1.f; vb[1].w -= 1.f;
        } else if (rel == 4) { // rows k8+4..7 = cols gn+0..3
          va[2].x -= 1.f; vb[2].y -= 1.f; va[3].z -= 1.f; vb[3].w -= 1.f;
        }
        unsigned tmpu[4][4];
#pragma unroll
        for (int kk2 = 0; kk2 < 4; ++kk2) {
          tmpu[0][kk2] = f2bf2(va[kk2].x, vb[kk2].x);
          tmpu[1][kk2] = f2bf2(va[kk2].y, vb[kk2].y);
          tmpu[2][kk2] = f2bf2(va[kk2].z, vb[kk2].z);
          tmpu[3][kk2] = f2bf2(va[kk2].w, vb[kk2].w);
        }
#pragma unroll
        for (int jj = 0; jj < 4; ++jj) {
          const int n = n4 + jj;
          const int slot = (((n >> 4) << 3) + kt) * 64 + LSWZ(n, lq);
          uint4 st = { tmpu[jj][0], tmpu[jj][1], tmpu[jj][2], tmpu[jj][3] };
          *(uint4*)&Bs[slot << 3] = st;
        }
      } else {
        __attribute__((aligned(16))) unsigned short tmp[4][8];
#pragma unroll
        for (int kk = 0; kk < 8; ++kk) {
          const ushort4 v = *(const ushort4*)(bBf + bBase + (long)(k8 + kk) * D + gn);
          tmp[0][kk] = v.x; tmp[1][kk] = v.y; tmp[2][kk] = v.z; tmp[3][kk] = v.w;
        }
#pragma unroll
        for (int jj = 0; jj < 4; ++jj) {
          const int n = n4 + jj;
          const int slot = (((n >> 4) << 3) + kt) * 64 + LSWZ(n, lq);
          *(uint4*)&Bs[slot << 3] = *(const uint4*)&tmp[jj][0];
        }
      }
    }
  }
  __syncthreads();

  // ---- MFMA: A from registers, B frags lane-contiguous from LDS (32 b128)
  f4 acc[4] = {{0.f,0.f,0.f,0.f},{0.f,0.f,0.f,0.f},
               {0.f,0.f,0.f,0.f},{0.f,0.f,0.f,0.f}};
#pragma unroll
  for (int kt = 0; kt < 8; ++kt) {
#pragma unroll
    for (int f = 0; f < 4; ++f) {
      const short8 b = *(const short8*)&Bs[((((f << 3) + kt) << 6) + lswz) << 3];
      acc[f] = __builtin_amdgcn_mfma_f32_16x16x32_bf16(areg[kt], b, acc[f], 0, 0, 0);
    }
  }

  // ---- epilogue: s = acc + devA (global re-read, L2-hot) + devB (LDS)
#pragma unroll
  for (int f = 0; f < 4; ++f) {
    const int gj_l = (f << 4) + lm;
    const int gj   = n0 + gj_l;                   // A's k/col index
#pragma unroll
    for (int r = 0; r < 4; ++r) {
      const int gi_l = (w << 4) + (lq4 << 2) + r; // local row
      const int giG  = m0 + gi_l;                 // B's k index
      float da;
      if (aF)
        da = aF[aBase + (long)giG * D + gj] - ((giG == gj) ? 1.f : 0.f);
      else
        da = bf2f(aBf[aBase + (long)giG * D + gj]);
      const int lqB  = (giG >> 3) & 3;
      const int slotB = (((gj_l >> 4) << 3) + (giG >> 5)) * 64 + LSWZ(gj_l, lqB);
      const float db = bf2f(Bs[(slotB << 3) + (giG & 7)]);
      acc[f][r] += da + db;
    }
  }
  __syncthreads();                                // all Bs reads done

  // ---- C restage (pitch 66: conflict-free b16 writes) then coalesced store
  unsigned short* Cs = Bs;                        // reuse (4224 shorts)
#pragma unroll
  for (int f = 0; f < 4; ++f)
#pragma unroll
    for (int r = 0; r < 4; ++r)
      Cs[((w << 4) + (lq4 << 2) + r) * 66 + (f << 4) + lm] = f2bf(acc[f][r]);
  __syncthreads();
  {
    const int row = t >> 2, c0g = (t & 3) << 4;   // 16 shorts per thread
    const unsigned int* Cw = (const unsigned int*)Cs;
    const int wb = row * 33 + ((t & 3) << 3);
    unsigned int wbuf[8];
#pragma unroll
    for (int i = 0; i < 8; ++i) wbuf[i] = Cw[wb + i];
    unsigned short* og = out + mat * (long)DD + (long)(m0 + row) * D + n0 + c0g;
    uint4 o0 = { wbuf[0], wbuf[1], wbuf[2], wbuf[3] };
    uint4 o1 = { wbuf[4], wbuf[5], wbuf[6], wbuf[7] };
    *(uint4*)og = o0;
    *((uint4*)og + 1) = o1;
  }
}

// v = v + v @ dev(M) over one bf16 span-product; barriers are WG-uniform.
__device__ __forceinline__ void apply_bf16(const unsigned short* __restrict__ Mb,
                                           float* v, float (*ps)[D],
                                           int t, int col, int kq) {
  const unsigned short* M = Mb + (long)(kq * 64) * D + col;
  float acc = 0.f;
#pragma unroll 8
  for (int i = 0; i < 64; ++i)
    acc += v[kq * 64 + i] * bf2f(M[(long)i * D]);
  ps[kq][col] = acc;
  __syncthreads();
  if (t < D) v[t] += ps[0][t] + ps[1][t] + ps[2][t] + ps[3][t];
  __syncthreads();
}

// ONE kernel for the whole tail. WG c targets prefix length L = 4c:
// greedy span descent (128*,64,32,16,8,4 -- identical matrices in identical
// order to the old scan_top8+descend chain), then exact fp32 bottom mat-vecs
// over m emitting out rows L..L+3 (c=255 also emits row 1024).
__global__ __launch_bounds__(1024) void tail_fused(
    const float* __restrict__ x,
    const unsigned short* __restrict__ sp128, const unsigned short* __restrict__ sp64,
    const unsigned short* __restrict__ sp32,  const unsigned short* __restrict__ sp16,
    const unsigned short* __restrict__ sp8,   const unsigned short* __restrict__ sp4,
    const float* __restrict__ m, float* __restrict__ out)
{
  __shared__ float v[D];
  __shared__ float ps[4][D];
  const int c = blockIdx.x, t = threadIdx.x, col = t & 255, kq = t >> 8;
  if (t < D) v[t] = x[t];
  __syncthreads();
  const int L = c << 2;

  int pos = 0;
#pragma unroll 1
  while (pos + 128 <= L) { apply_bf16(sp128 + (long)(pos >> 7) * DD, v, ps, t, col, kq); pos += 128; }
  if (pos + 64 <= L) { apply_bf16(sp64 + (long)(pos >> 6) * DD, v, ps, t, col, kq); pos += 64; }
  if (pos + 32 <= L) { apply_bf16(sp32 + (long)(pos >> 5) * DD, v, ps, t, col, kq); pos += 32; }
  if (pos + 16 <= L) { apply_bf16(sp16 + (long)(pos >> 4) * DD, v, ps, t, col, kq); pos += 16; }
  if (pos + 8 <= L)  { apply_bf16(sp8  + (long)(pos >> 3) * DD, v, ps, t, col, kq); pos += 8; }
  if (pos + 4 <= L)  { apply_bf16(sp4  + (long)(pos >> 2) * DD, v, ps, t, col, kq); pos += 4; }

  // bottom: emit rows with exact fp32 mat-vecs over m
  if (t < D) out[(long)L * D + t] = v[t];
  const int steps = (c == 255) ? 4 : 3;
#pragma unroll 1
  for (int s = 0; s < steps; ++s) {
    const float* M = m + (long)(L + s) * DD + (long)(kq * 64) * D + col;
    float acc = 0.f;
#pragma unroll 8
    for (int i = 0; i < 64; ++i)
      acc += v[kq * 64 + i] * M[(long)i * D];
    ps[kq][col] = acc;
    __syncthreads();
    if (t < D) {
      const float s2 = ps[0][t] + ps[1][t] + ps[2][t] + ps[3][t];
      v[t] = s2;
      out[(long)(L + s + 1) * D + t] = s2;
    }
    __syncthreads();
  }
}

// correctness-only fallback if ws is too small: fully sequential chain
__global__ __launch_bounds__(256) void fallback_seq(
    const float* __restrict__ x, const float* __restrict__ m,
    float* __restrict__ out)
{
  __shared__ float v[D];
  const int t = threadIdx.x;
  v[t] = x[t];
  __syncthreads();
  for (int k = 0; k < 1024; ++k) {
    out[(long)k * D + t] = v[t];
    const float* M = m + (long)k * DD;
    float acc = 0.f;
    for (int i = 0; i < D; ++i) acc += v[i] * M[(long)i * D + t];
    __syncthreads();
    v[t] = acc;
    __syncthreads();
  }
  out[(long)1024 * D + t] = v[t];
}

extern "C" void kernel_launch(void* const* d_in, const int* in_sizes, int n_in,
                              void* d_out, int out_size, void* d_ws, size_t ws_size,
                              hipStream_t stream) {
  const float* x = (const float*)d_in[0];   // [1,256] fp32
  const float* m = (const float*)d_in[1];   // [1024,256,256] fp32
  float* out = (float*)d_out;               // [1025,256] fp32

  char* w8 = (char*)d_ws;
  const size_t MB = 1048576;
  const dim3 blk(256), vblk(1024);

  if (ws_size >= 127 * MB) {
    // ---- wide path: full-width tree, one launch per level (7 gemms + tail)
    unsigned short* T2   = (unsigned short*)(w8);             // 64 MiB span-2  (512)
    unsigned short* Qb   = (unsigned short*)(w8 + 64 * MB);   // 32 MiB span-4  (256)
    unsigned short* Q2   = (unsigned short*)(w8 + 96 * MB);   // 16 MiB span-8  (128)
    unsigned short* Q4   = (unsigned short*)(w8 + 112 * MB);  //  8 MiB span-16 (64)
    unsigned short* Rm   = (unsigned short*)(w8 + 120 * MB);  //  4 MiB span-32 (32)
    unsigned short* S64  = (unsigned short*)(w8 + 124 * MB);  //  2 MiB span-64 (16)
    unsigned short* S128 = (unsigned short*)(w8 + 126 * MB);  //  1 MiB span-128 (8)
    gemm_mfma<<<dim3(8192), blk, 0, stream>>>(m, nullptr, 2, 0, m, nullptr, 2, 1, T2);
    gemm_mfma<<<dim3(4096), blk, 0, stream>>>(nullptr, T2, 2, 0, nullptr, T2, 2, 1, Qb);
    gemm_mfma<<<dim3(2048), blk, 0, stream>>>(nullptr, Qb, 2, 0, nullptr, Qb, 2, 1, Q2);
    gemm_mfma<<<dim3(1024), blk, 0, stream>>>(nullptr, Q2, 2, 0, nullptr, Q2, 2, 1, Q4);
    gemm_mfma<<<dim3(512),  blk, 0, stream>>>(nullptr, Q4, 2, 0, nullptr, Q4, 2, 1, Rm);
    gemm_mfma<<<dim3(256),  blk, 0, stream>>>(nullptr, Rm, 2, 0, nullptr, Rm, 2, 1, S64);
    gemm_mfma<<<dim3(128),  blk, 0, stream>>>(nullptr, S64, 2, 0, nullptr, S64, 2, 1, S128);
    tail_fused<<<dim3(256), vblk, 0, stream>>>(x, S128, S64, Rm, Q4, Q2, Qb, m, out);
  } else if (ws_size >= 67108864) {
    // ---- narrow path (half-split tree), fused tail
    unsigned short* buf0 = (unsigned short*)(w8);
    unsigned short* Qb   = (unsigned short*)(w8 + 33554432);  // span-4, 256 mats
    unsigned short* Q2   = (unsigned short*)(w8);             // 16 MiB span-8
    unsigned short* Q4   = (unsigned short*)(w8 + 16777216);  //  8 MiB span-16
    unsigned short* Rm   = (unsigned short*)(w8 + 25165824);  //  4 MiB span-32
    unsigned short* S64  = (unsigned short*)(w8 + 29360128);  //  2 MiB span-64
    unsigned short* S128 = (unsigned short*)(w8 + 31457280);  //  1 MiB span-128
    gemm_mfma<<<dim3(4096), blk, 0, stream>>>(m, nullptr, 2, 0, m, nullptr, 2, 1, buf0);
    gemm_mfma<<<dim3(2048), blk, 0, stream>>>(nullptr, buf0, 2, 0, nullptr, buf0, 2, 1, Qb);
    gemm_mfma<<<dim3(4096), blk, 0, stream>>>(m + 512L * DD, nullptr, 2, 0,
                                              m + 512L * DD, nullptr, 2, 1, buf0);
    gemm_mfma<<<dim3(2048), blk, 0, stream>>>(nullptr, buf0, 2, 0, nullptr, buf0, 2, 1,
                                              Qb + 128L * DD);
    gemm_mfma<<<dim3(2048), blk, 0, stream>>>(nullptr, Qb, 2, 0, nullptr, Qb, 2, 1, Q2);
    gemm_mfma<<<dim3(1024), blk, 0, stream>>>(nullptr, Q2, 2, 0, nullptr, Q2, 2, 1, Q4);
    gemm_mfma<<<dim3(512),  blk, 0, stream>>>(nullptr, Q4, 2, 0, nullptr, Q4, 2, 1, Rm);
    gemm_mfma<<<dim3(256),  blk, 0, stream>>>(nullptr, Rm, 2, 0, nullptr, Rm, 2, 1, S64);
    gemm_mfma<<<dim3(128),  blk, 0, stream>>>(nullptr, S64, 2, 0, nullptr, S64, 2, 1, S128);
    tail_fused<<<dim3(256), vblk, 0, stream>>>(x, S128, S64, Rm, Q4, Q2, Qb, m, out);
  } else {
    fallback_seq<<<dim3(1), blk, 0, stream>>>(x, m, out);
  }
}

// Round 4
// 569.059 us; speedup vs baseline: 1.0133x; 1.0036x over previous
//
#include <hip/hip_runtime.h>
#include <hip/hip_bf16.h>

// ============================================================================
// Hybrid matrix prefix scan:  res[k] = x @ (m_0 ... m_{k-1}),  N=1024, D=256.
// Deviation form everywhere: store P - I in bf16; combine is exact:
//   dev(XY) = devX + devY + devX@devY.
// Round 7 (single-variable occupancy A/B vs R6):
//  (a) restore __launch_bounds__(256,4) -> VGPR<=128 -> 4 blocks/CU target
//      (16 waves/CU). R6 without the bound likely sat at VGPR>128 = 2 blocks.
//  (b) B-staging temps halved (two-pass va[2]/vb[2], identical fp32 ops in
//      identical order) so 128 VGPR is reachable WITHOUT spill: hand-counted
//      peak live ~56 VGPR.
//  (c) everything else bit-identical to R6: A frags direct to regs with
//      branch diag fixup, 32 KiB LDS, packed bf16 cvt, fused tail, wide
//      8-launch tree.
// Interpretation rule (pre-committed): win => occupancy was binding, push
// further; wash => gemm not occupancy-bound, residual = fill + launch drains.
// ============================================================================

#define D 256
#define DD 65536

typedef __attribute__((ext_vector_type(8))) short short8;
typedef __attribute__((ext_vector_type(4))) float f4;

__device__ __forceinline__ float bf2f(unsigned short u) {
  return __uint_as_float(((unsigned)u) << 16);
}
// native RNE converts -- compiler emits v_cvt_pk_bf16_f32 (learn_hip m240)
__device__ __forceinline__ unsigned short f2bf(float f) {
  __hip_bfloat16 h = __float2bfloat16(f);
  unsigned short u;
  __builtin_memcpy(&u, &h, 2);
  return u;
}
__device__ __forceinline__ unsigned f2bf2(float lo, float hi) {
  __hip_bfloat162 h = __float22bfloat162_rn(make_float2(lo, hi));
  unsigned u;
  __builtin_memcpy(&u, &h, 4);
  return u;
}
// fragment-order slot lane index (see R3): frag reads lane-contiguous b128.
#define LSWZ(i15, lq) (((((i15) & 15)) + ((lq) << 4)) ^ (lq))

// out[mat] = devA + devB + devA@devB (bf16 dev out), MFMA 16x16x32 bf16.
// 64x64 tile/block (16 blocks/mat), 4 waves. B staged full-K in LDS (32 KiB);
// A fragments live in registers. Block swizzle: xcd = bx&7; all 16 tiles of a
// mat on the same XCD (requires gridDim/16 divisible by 8).
__global__ __launch_bounds__(256, 4) void gemm_mfma(
    const float* __restrict__ aF, const unsigned short* __restrict__ aBf,
    long aMul, long aOff,
    const float* __restrict__ bF, const unsigned short* __restrict__ bBf,
    long bMul, long bOff,
    unsigned short* __restrict__ out)
{
  __shared__ __attribute__((aligned(16))) unsigned short Bs[16384]; // 32 KiB

  const int  bx  = blockIdx.x;
  const int  nmb = ((int)gridDim.x) >> 4;         // mats this dispatch (mult of 8)
  const int  xcd = bx & 7, q = bx >> 3;
  const long mat = (long)(xcd * (nmb >> 3)) + (q >> 4);
  const int  tile = q & 15;
  const int  m0 = (tile >> 2) << 6, n0 = (tile & 3) << 6;
  const long aBase = (mat * aMul + aOff) * (long)DD;
  const long bBase = (mat * bMul + bOff) * (long)DD;
  const int t = threadIdx.x;
  const int w = t >> 6, l = t & 63, lm = l & 15, lq4 = l >> 4;
  const int lswz = l ^ lq4;

  // ---- A fragments straight to registers.
  // Lane l of wave w feeds MFMA row R = m0+16w+(l&15), k = 32kt + 8*lq4 + j.
  const int R = m0 + (w << 4) + lm;
  short8 areg[8];
  if (aF) {
    const float* ap = aF + aBase + (long)R * D + (lq4 << 3);
#pragma unroll
    for (int kt = 0; kt < 8; ++kt) {
      float4 v0 = *(const float4*)(ap + (kt << 5));
      float4 v1 = *(const float4*)(ap + (kt << 5) + 4);
      // diag fixup: row R's diagonal col R lies in this 8-k strip iff
      // (R>>3) == 4*kt + lq4; then the component is j = R & 7.
      if ((R >> 3) == (kt << 2) + lq4) {
        const int j = R & 7;
        if      (j == 0) v0.x -= 1.f;
        else if (j == 1) v0.y -= 1.f;
        else if (j == 2) v0.z -= 1.f;
        else if (j == 3) v0.w -= 1.f;
        else if (j == 4) v1.x -= 1.f;
        else if (j == 5) v1.y -= 1.f;
        else if (j == 6) v1.z -= 1.f;
        else             v1.w -= 1.f;
      }
      union { short8 v8; unsigned u[4]; } ou;
      ou.u[0] = f2bf2(v0.x, v0.y);
      ou.u[1] = f2bf2(v0.z, v0.w);
      ou.u[2] = f2bf2(v1.x, v1.y);
      ou.u[3] = f2bf2(v1.z, v1.w);
      areg[kt] = ou.v8;
    }
  } else {
    const unsigned short* ap = aBf + aBase + (long)R * D + (lq4 << 3);
#pragma unroll
    for (int kt = 0; kt < 8; ++kt)
      areg[kt] = *(const short8*)(ap + (kt << 5));
  }

  // ---- stage B cols [n0,n0+64) x k[0,256) (register transpose into LDS)
  {
    const int n4 = (t & 15) << 2;
    const int kb0 = (t >> 4) << 3;
    const int gn = n0 + n4;
#pragma unroll
    for (int kp = 0; kp < 2; ++kp) {
      const int k8 = kb0 + (kp << 7);
      const int lq = (k8 >> 3) & 3, kt = k8 >> 5;
      if (bF) {
        // two-pass staging (va[2]/vb[2]): same fp32 ops, same order as the
        // one-pass va[4]/vb[4] version, but ~16 fewer live VGPRs at peak.
        unsigned tmpu[4][4];
        const int rel = gn - k8;
#pragma unroll
        for (int h = 0; h < 2; ++h) {
          float4 va[2], vb[2];
#pragma unroll
          for (int p2 = 0; p2 < 2; ++p2) {
            va[p2] = *(const float4*)(bF + bBase + (long)(k8 + 4 * h + 2 * p2) * D + gn);
            vb[p2] = *(const float4*)(bF + bBase + (long)(k8 + 4 * h + 2 * p2 + 1) * D + gn);
          }
          // cols [gn,gn+4) have diag rows [gn,gn+4); they fall in this
          // 4-row half iff rel == 4h (gn,k8 4-/8-aligned).
          if (rel == 4 * h) {
            va[0].x -= 1.f; vb[0].y -= 1.f; va[1].z -= 1.f; vb[1].w -= 1.f;
          }
          tmpu[0][2 * h + 0] = f2bf2(va[0].x, vb[0].x);
          tmpu[0][2 * h + 1] = f2bf2(va[1].x, vb[1].x);
          tmpu[1][2 * h + 0] = f2bf2(va[0].y, vb[0].y);
          tmpu[1][2 * h + 1] = f2bf2(va[1].y, vb[1].y);
          tmpu[2][2 * h + 0] = f2bf2(va[0].z, vb[0].z);
          tmpu[2][2 * h + 1] = f2bf2(va[1].z, vb[1].z);
          tmpu[3][2 * h + 0] = f2bf2(va[0].w, vb[0].w);
          tmpu[3][2 * h + 1] = f2bf2(va[1].w, vb[1].w);
        }
#pragma unroll
        for (int jj = 0; jj < 4; ++jj) {
          const int n = n4 + jj;
          const int slot = (((n >> 4) << 3) + kt) * 64 + LSWZ(n, lq);
          uint4 st = { tmpu[jj][0], tmpu[jj][1], tmpu[jj][2], tmpu[jj][3] };
          *(uint4*)&Bs[slot << 3] = st;
        }
      } else {
        __attribute__((aligned(16))) unsigned short tmp[4][8];
#pragma unroll
        for (int kk = 0; kk < 8; ++kk) {
          const ushort4 v = *(const ushort4*)(bBf + bBase + (long)(k8 + kk) * D + gn);
          tmp[0][kk] = v.x; tmp[1][kk] = v.y; tmp[2][kk] = v.z; tmp[3][kk] = v.w;
        }
#pragma unroll
        for (int jj = 0; jj < 4; ++jj) {
          const int n = n4 + jj;
          const int slot = (((n >> 4) << 3) + kt) * 64 + LSWZ(n, lq);
          *(uint4*)&Bs[slot << 3] = *(const uint4*)&tmp[jj][0];
        }
      }
    }
  }
  __syncthreads();

  // ---- MFMA: A from registers, B frags lane-contiguous from LDS (32 b128)
  f4 acc[4] = {{0.f,0.f,0.f,0.f},{0.f,0.f,0.f,0.f},
               {0.f,0.f,0.f,0.f},{0.f,0.f,0.f,0.f}};
#pragma unroll
  for (int kt = 0; kt < 8; ++kt) {
#pragma unroll
    for (int f = 0; f < 4; ++f) {
      const short8 b = *(const short8*)&Bs[((((f << 3) + kt) << 6) + lswz) << 3];
      acc[f] = __builtin_amdgcn_mfma_f32_16x16x32_bf16(areg[kt], b, acc[f], 0, 0, 0);
    }
  }

  // ---- epilogue: s = acc + devA (global re-read, L2-hot) + devB (LDS)
#pragma unroll
  for (int f = 0; f < 4; ++f) {
    const int gj_l = (f << 4) + lm;
    const int gj   = n0 + gj_l;                   // A's k/col index
#pragma unroll
    for (int r = 0; r < 4; ++r) {
      const int gi_l = (w << 4) + (lq4 << 2) + r; // local row
      const int giG  = m0 + gi_l;                 // B's k index
      float da;
      if (aF)
        da = aF[aBase + (long)giG * D + gj] - ((giG == gj) ? 1.f : 0.f);
      else
        da = bf2f(aBf[aBase + (long)giG * D + gj]);
      const int lqB  = (giG >> 3) & 3;
      const int slotB = (((gj_l >> 4) << 3) + (giG >> 5)) * 64 + LSWZ(gj_l, lqB);
      const float db = bf2f(Bs[(slotB << 3) + (giG & 7)]);
      acc[f][r] += da + db;
    }
  }
  __syncthreads();                                // all Bs reads done

  // ---- C restage (pitch 66: conflict-free b16 writes) then coalesced store
  unsigned short* Cs = Bs;                        // reuse (4224 shorts)
#pragma unroll
  for (int f = 0; f < 4; ++f)
#pragma unroll
    for (int r = 0; r < 4; ++r)
      Cs[((w << 4) + (lq4 << 2) + r) * 66 + (f << 4) + lm] = f2bf(acc[f][r]);
  __syncthreads();
  {
    const int row = t >> 2, c0g = (t & 3) << 4;   // 16 shorts per thread
    const unsigned int* Cw = (const unsigned int*)Cs;
    const int wb = row * 33 + ((t & 3) << 3);
    unsigned int wbuf[8];
#pragma unroll
    for (int i = 0; i < 8; ++i) wbuf[i] = Cw[wb + i];
    unsigned short* og = out + mat * (long)DD + (long)(m0 + row) * D + n0 + c0g;
    uint4 o0 = { wbuf[0], wbuf[1], wbuf[2], wbuf[3] };
    uint4 o1 = { wbuf[4], wbuf[5], wbuf[6], wbuf[7] };
    *(uint4*)og = o0;
    *((uint4*)og + 1) = o1;
  }
}

// v = v + v @ dev(M) over one bf16 span-product; barriers are WG-uniform.
__device__ __forceinline__ void apply_bf16(const unsigned short* __restrict__ Mb,
                                           float* v, float (*ps)[D],
                                           int t, int col, int kq) {
  const unsigned short* M = Mb + (long)(kq * 64) * D + col;
  float acc = 0.f;
#pragma unroll 8
  for (int i = 0; i < 64; ++i)
    acc += v[kq * 64 + i] * bf2f(M[(long)i * D]);
  ps[kq][col] = acc;
  __syncthreads();
  if (t < D) v[t] += ps[0][t] + ps[1][t] + ps[2][t] + ps[3][t];
  __syncthreads();
}

// ONE kernel for the whole tail. WG c targets prefix length L = 4c:
// greedy span descent (128*,64,32,16,8,4 -- identical matrices in identical
// order to the old scan_top8+descend chain), then exact fp32 bottom mat-vecs
// over m emitting out rows L..L+3 (c=255 also emits row 1024).
__global__ __launch_bounds__(1024) void tail_fused(
    const float* __restrict__ x,
    const unsigned short* __restrict__ sp128, const unsigned short* __restrict__ sp64,
    const unsigned short* __restrict__ sp32,  const unsigned short* __restrict__ sp16,
    const unsigned short* __restrict__ sp8,   const unsigned short* __restrict__ sp4,
    const float* __restrict__ m, float* __restrict__ out)
{
  __shared__ float v[D];
  __shared__ float ps[4][D];
  const int c = blockIdx.x, t = threadIdx.x, col = t & 255, kq = t >> 8;
  if (t < D) v[t] = x[t];
  __syncthreads();
  const int L = c << 2;

  int pos = 0;
#pragma unroll 1
  while (pos + 128 <= L) { apply_bf16(sp128 + (long)(pos >> 7) * DD, v, ps, t, col, kq); pos += 128; }
  if (pos + 64 <= L) { apply_bf16(sp64 + (long)(pos >> 6) * DD, v, ps, t, col, kq); pos += 64; }
  if (pos + 32 <= L) { apply_bf16(sp32 + (long)(pos >> 5) * DD, v, ps, t, col, kq); pos += 32; }
  if (pos + 16 <= L) { apply_bf16(sp16 + (long)(pos >> 4) * DD, v, ps, t, col, kq); pos += 16; }
  if (pos + 8 <= L)  { apply_bf16(sp8  + (long)(pos >> 3) * DD, v, ps, t, col, kq); pos += 8; }
  if (pos + 4 <= L)  { apply_bf16(sp4  + (long)(pos >> 2) * DD, v, ps, t, col, kq); pos += 4; }

  // bottom: emit rows with exact fp32 mat-vecs over m
  if (t < D) out[(long)L * D + t] = v[t];
  const int steps = (c == 255) ? 4 : 3;
#pragma unroll 1
  for (int s = 0; s < steps; ++s) {
    const float* M = m + (long)(L + s) * DD + (long)(kq * 64) * D + col;
    float acc = 0.f;
#pragma unroll 8
    for (int i = 0; i < 64; ++i)
      acc += v[kq * 64 + i] * M[(long)i * D];
    ps[kq][col] = acc;
    __syncthreads();
    if (t < D) {
      const float s2 = ps[0][t] + ps[1][t] + ps[2][t] + ps[3][t];
      v[t] = s2;
      out[(long)(L + s + 1) * D + t] = s2;
    }
    __syncthreads();
  }
}

// correctness-only fallback if ws is too small: fully sequential chain
__global__ __launch_bounds__(256) void fallback_seq(
    const float* __restrict__ x, const float* __restrict__ m,
    float* __restrict__ out)
{
  __shared__ float v[D];
  const int t = threadIdx.x;
  v[t] = x[t];
  __syncthreads();
  for (int k = 0; k < 1024; ++k) {
    out[(long)k * D + t] = v[t];
    const float* M = m + (long)k * DD;
    float acc = 0.f;
    for (int i = 0; i < D; ++i) acc += v[i] * M[(long)i * D + t];
    __syncthreads();
    v[t] = acc;
    __syncthreads();
  }
  out[(long)1024 * D + t] = v[t];
}

extern "C" void kernel_launch(void* const* d_in, const int* in_sizes, int n_in,
                              void* d_out, int out_size, void* d_ws, size_t ws_size,
                              hipStream_t stream) {
  const float* x = (const float*)d_in[0];   // [1,256] fp32
  const float* m = (const float*)d_in[1];   // [1024,256,256] fp32
  float* out = (float*)d_out;               // [1025,256] fp32

  char* w8 = (char*)d_ws;
  const size_t MB = 1048576;
  const dim3 blk(256), vblk(1024);

  if (ws_size >= 127 * MB) {
    // ---- wide path: full-width tree, one launch per level (7 gemms + tail)
    unsigned short* T2   = (unsigned short*)(w8);             // 64 MiB span-2  (512)
    unsigned short* Qb   = (unsigned short*)(w8 + 64 * MB);   // 32 MiB span-4  (256)
    unsigned short* Q2   = (unsigned short*)(w8 + 96 * MB);   // 16 MiB span-8  (128)
    unsigned short* Q4   = (unsigned short*)(w8 + 112 * MB);  //  8 MiB span-16 (64)
    unsigned short* Rm   = (unsigned short*)(w8 + 120 * MB);  //  4 MiB span-32 (32)
    unsigned short* S64  = (unsigned short*)(w8 + 124 * MB);  //  2 MiB span-64 (16)
    unsigned short* S128 = (unsigned short*)(w8 + 126 * MB);  //  1 MiB span-128 (8)
    gemm_mfma<<<dim3(8192), blk, 0, stream>>>(m, nullptr, 2, 0, m, nullptr, 2, 1, T2);
    gemm_mfma<<<dim3(4096), blk, 0, stream>>>(nullptr, T2, 2, 0, nullptr, T2, 2, 1, Qb);
    gemm_mfma<<<dim3(2048), blk, 0, stream>>>(nullptr, Qb, 2, 0, nullptr, Qb, 2, 1, Q2);
    gemm_mfma<<<dim3(1024), blk, 0, stream>>>(nullptr, Q2, 2, 0, nullptr, Q2, 2, 1, Q4);
    gemm_mfma<<<dim3(512),  blk, 0, stream>>>(nullptr, Q4, 2, 0, nullptr, Q4, 2, 1, Rm);
    gemm_mfma<<<dim3(256),  blk, 0, stream>>>(nullptr, Rm, 2, 0, nullptr, Rm, 2, 1, S64);
    gemm_mfma<<<dim3(128),  blk, 0, stream>>>(nullptr, S64, 2, 0, nullptr, S64, 2, 1, S128);
    tail_fused<<<dim3(256), vblk, 0, stream>>>(x, S128, S64, Rm, Q4, Q2, Qb, m, out);
  } else if (ws_size >= 67108864) {
    // ---- narrow path (half-split tree), fused tail
    unsigned short* buf0 = (unsigned short*)(w8);
    unsigned short* Qb   = (unsigned short*)(w8 + 33554432);  // span-4, 256 mats
    unsigned short* Q2   = (unsigned short*)(w8);             // 16 MiB span-8
    unsigned short* Q4   = (unsigned short*)(w8 + 16777216);  //  8 MiB span-16
    unsigned short* Rm   = (unsigned short*)(w8 + 25165824);  //  4 MiB span-32
    unsigned short* S64  = (unsigned short*)(w8 + 29360128);  //  2 MiB span-64
    unsigned short* S128 = (unsigned short*)(w8 + 31457280);  //  1 MiB span-128
    gemm_mfma<<<dim3(4096), blk, 0, stream>>>(m, nullptr, 2, 0, m, nullptr, 2, 1, buf0);
    gemm_mfma<<<dim3(2048), blk, 0, stream>>>(nullptr, buf0, 2, 0, nullptr, buf0, 2, 1, Qb);
    gemm_mfma<<<dim3(4096), blk, 0, stream>>>(m + 512L * DD, nullptr, 2, 0,
                                              m + 512L * DD, nullptr, 2, 1, buf0);
    gemm_mfma<<<dim3(2048), blk, 0, stream>>>(nullptr, buf0, 2, 0, nullptr, buf0, 2, 1,
                                              Qb + 128L * DD);
    gemm_mfma<<<dim3(2048), blk, 0, stream>>>(nullptr, Qb, 2, 0, nullptr, Qb, 2, 1, Q2);
    gemm_mfma<<<dim3(1024), blk, 0, stream>>>(nullptr, Q2, 2, 0, nullptr, Q2, 2, 1, Q4);
    gemm_mfma<<<dim3(512),  blk, 0, stream>>>(nullptr, Q4, 2, 0, nullptr, Q4, 2, 1, Rm);
    gemm_mfma<<<dim3(256),  blk, 0, stream>>>(nullptr, Rm, 2, 0, nullptr, Rm, 2, 1, S64);
    gemm_mfma<<<dim3(128),  blk, 0, stream>>>(nullptr, S64, 2, 0, nullptr, S64, 2, 1, S128);
    tail_fused<<<dim3(256), vblk, 0, stream>>>(x, S128, S64, Rm, Q4, Q2, Qb, m, out);
  } else {
    fallback_seq<<<dim3(1), blk, 0, stream>>>(x, m, out);
  }
}